// Round 8
// baseline (263.986 us; speedup 1.0000x reference)
//
#include <hip/hip_runtime.h>
#include <math.h>

#define B_ 16
#define SEQ_ 8192
#define C_ 192
#define H_ 16
#define OV_ 4
#define G_ 6
#define K_ 1024
#define D_ 8
#define DG_ 2048
#define W_ 512
#define T_ 128
#define TT 4
#define OUT_ELEMS (B_ * SEQ_ * C_)   // 25165824

// workspace layout:
//   pd_perm : float [G*DG*D]  = 98304 floats   @ byte 0
//   pu_perm : float [G*D*DG]  = 98304 floats   @ byte 393216
//   cbn_d   : double[G*K*D]   = 49152 doubles  @ byte 786432
// total = 1179648 bytes

// d' = h*128 + ul  <->  group-local d = ul*16 + h,  u = g*128 + ul = o*192 + c
// o*192 + c == u, so z addresses are LINEAR in u:
//   z[t][dp=h*128+ul] = zb[h*98304 + (tc*4+t)*768 + g*128 + ul]
//
// Round-8: round-0 kernel minus the phase-0 LDS transpose. A thread's phase-1
// dp-rows are DEFINED as the 8 floats it loads (dp4(j)..+3, j=0,1; the (h,ul)
// of slot v=j*256+tid is t-independent, so all 4 frames share the thread's
// dp-rows). z goes straight from registers into the fp64 FMAs; the 32 KB zs
// buffer and its barrier vanish; part_d is the lone 32 KB LDS buffer.
// Phase 1+1.5 run per t-PAIR so the live-set (acc2 32 + z 16 + pd 32 ~= 90)
// dies into LDS before phase 2 loads cd[4][8] -- the spill line is ~128 live:
//   - rounds 1/2 (launch-bounds clamp) and 7 (zpref across phases) all spilled
//     -> symmetric +HBM fetch AND write. WRITE_SIZE != 98496 KB = spill.
//   - direct permuted pd/pu reads (512B lane stride) -> 2x vq_main. Keep prep.
//   - ~118 us of headline is harness poison/launch overhead, not kernel time.

__global__ __launch_bounds__(256) void vq_prep(
    const float* __restrict__ pd, const float* __restrict__ pu,
    const float* __restrict__ cb,
    float* __restrict__ pd_p, float* __restrict__ pu_p,
    double* __restrict__ cbn, float* __restrict__ loss_slots)
{
  int i = blockIdx.x * 256 + threadIdx.x;
  if (i < 98304) {                       // pd_perm[g][d'][e]
    int e = i & 7, dp = (i >> 3) & 2047, g = i >> 14;
    int h = dp >> 7, ul = dp & 127, d = (ul << 4) + h;
    pd_p[i] = pd[(g << 14) + (d << 3) + e];
  } else if (i < 196608) {               // pu_perm[g][e][d']
    int i2 = i - 98304;
    int dp = i2 & 2047, e = (i2 >> 11) & 7, g = i2 >> 14;
    int h = dp >> 7, ul = dp & 127, d = (ul << 4) + h;
    pu_p[i2] = pu[(g << 14) + (e << 11) + d];
  } else if (i < 202752) {               // normalized codebooks, fp64
    int j = i - 196608;                  // j = g*1024 + k
    const float* row = cb + (j << 3);
    double ss = 0.0;
    #pragma unroll
    for (int e = 0; e < 8; ++e) { double x = (double)row[e]; ss += x * x; }
    double inv = 1.0 / fmax(sqrt(ss), 1e-12);
    #pragma unroll
    for (int e = 0; e < 8; ++e) cbn[(j << 3) + e] = (double)row[e] * inv;
  } else if (i < 202784) {               // zero the 32 loss accumulators
    loss_slots[i - 202752] = 0.0f;
  }
}

__global__ __launch_bounds__(256) void vq_main(
    const float* __restrict__ z, const float* __restrict__ cb,
    const float* __restrict__ pd_p, const float* __restrict__ pu_p,
    const double* __restrict__ cbn,
    float* __restrict__ out, float* __restrict__ loss_slots)
{
  __shared__ double part_d[16 * 256];   // 32 KB reduction buffer (16 slots x 256)
  __shared__ double ze_d[TT * 8];
  __shared__ float  zq_s[TT * 8];
  __shared__ double wr_s[4][TT];
  __shared__ int    wr_k[4][TT];
  __shared__ float  lossv[TT];

  const int tid = threadIdx.x;
  const int tc  = blockIdx.x;   // 0..31 (chunk of TT=4 grouped frames)
  const int g   = blockIdx.y;   // 0..5
  const int b   = blockIdx.z;   // 0..15

  const float* zb = z + (size_t)b * (SEQ_ * C_);

  // thread's two float4 slots (t-independent): v = j*256 + tid
  const int h0  = tid >> 5;            // j=0: h in 0..7
  const int ul0 = (tid & 31) << 2;
  const int h1  = h0 + 8;              // j=1: h in 8..15
  const int dp40 = (h0 << 7) + ul0;    // 4 consecutive dp rows
  const int dp41 = (h1 << 7) + ul0;

  // ---------- phase 1 + 1.5: z_e via register-held z, per t-pair ----------
  #pragma unroll
  for (int tp = 0; tp < 2; ++tp) {
    // z loads for frames t = 2tp, 2tp+1 (issued up front, high MLP)
    float4 zf[2][2];                   // [t2][j]
    #pragma unroll
    for (int t2 = 0; t2 < 2; ++t2) {
      const size_t rb = (size_t)((tc * TT + (tp * 2 + t2)) * OV_) * 192 + (g << 7) + ul0;
      zf[t2][0] = *(const float4*)(zb + (size_t)h0 * (512 * 192) + rb);
      zf[t2][1] = *(const float4*)(zb + (size_t)h1 * (512 * 192) + rb);
    }

    double acc2[2][8];
    #pragma unroll
    for (int t2 = 0; t2 < 2; ++t2)
      #pragma unroll
      for (int e = 0; e < 8; ++e) acc2[t2][e] = 0.0;

    #pragma unroll
    for (int j = 0; j < 2; ++j) {
      const int dp4 = j ? dp41 : dp40;
      const float4* pr = (const float4*)(pd_p + (((g << 11) + dp4) << 3));
      #pragma unroll
      for (int l = 0; l < 4; ++l) {
        const float4 pe0 = pr[l * 2];        // row dp4+l, e 0..3
        const float4 pe1 = pr[l * 2 + 1];    // row dp4+l, e 4..7
        #pragma unroll
        for (int t2 = 0; t2 < 2; ++t2) {
          const float* zp = (const float*)&zf[t2][j];
          const double zv = (double)zp[l];
          acc2[t2][0] = fma(zv, (double)pe0.x, acc2[t2][0]);
          acc2[t2][1] = fma(zv, (double)pe0.y, acc2[t2][1]);
          acc2[t2][2] = fma(zv, (double)pe0.z, acc2[t2][2]);
          acc2[t2][3] = fma(zv, (double)pe0.w, acc2[t2][3]);
          acc2[t2][4] = fma(zv, (double)pe1.x, acc2[t2][4]);
          acc2[t2][5] = fma(zv, (double)pe1.y, acc2[t2][5]);
          acc2[t2][6] = fma(zv, (double)pe1.z, acc2[t2][6]);
          acc2[t2][7] = fma(zv, (double)pe1.w, acc2[t2][7]);
        }
      }
    }

    // block reduction: 16 slots (t2*8+e), 256 partials each
    __syncthreads();   // tp=0: first use; tp=1: prior round's reads done
    #pragma unroll
    for (int t2 = 0; t2 < 2; ++t2)
      #pragma unroll
      for (int e = 0; e < 8; ++e)
        part_d[((t2 << 3) + e) * 256 + tid] = acc2[t2][e];
    __syncthreads();
    const int slot = tid >> 4, jj = tid & 15;
    double partial = 0.0;
    #pragma unroll
    for (int s = 0; s < 16; ++s) {
      int p = (s + tid) & 15;          // rotate to spread banks
      partial += part_d[slot * 256 + jj * 16 + p];
    }
    partial += __shfl_down(partial, 8);
    partial += __shfl_down(partial, 4);
    partial += __shfl_down(partial, 2);
    partial += __shfl_down(partial, 1);
    if (jj == 0) ze_d[(tp << 4) + slot] = partial;   // (2tp+t2)*8+e, slot=t2*8+e
  }
  __syncthreads();

  // ---------- phase 2: argmax over 1024 codes (fp64 sim, first-max tie-break) ----
  double cd[4][8];
  #pragma unroll
  for (int q = 0; q < 4; ++q) {
    const double* cr = cbn + (((g << 10) + (q << 8) + tid) << 3);
    #pragma unroll
    for (int e = 0; e < 8; ++e) cd[q][e] = cr[e];
  }
  double bs[TT]; int bk[TT];
  #pragma unroll
  for (int t = 0; t < TT; ++t) {
    double zr[8];
    #pragma unroll
    for (int e = 0; e < 8; ++e) zr[e] = ze_d[t * 8 + e];
    bs[t] = -1.0e300; bk[t] = 0x7fffffff;
    #pragma unroll
    for (int q = 0; q < 4; ++q) {
      double s = 0.0;
      #pragma unroll
      for (int e = 0; e < 8; ++e) s = fma(zr[e], cd[q][e], s);
      int k = (q << 8) + tid;          // ascending within thread -> strict > keeps min k
      if (s > bs[t]) { bs[t] = s; bk[t] = k; }
    }
  }
  #pragma unroll
  for (int m = 32; m >= 1; m >>= 1) {
    #pragma unroll
    for (int t = 0; t < TT; ++t) {
      double os = __shfl_xor(bs[t], m);
      int    ok = __shfl_xor(bk[t], m);
      if (os > bs[t] || (os == bs[t] && ok < bk[t])) { bs[t] = os; bk[t] = ok; }
    }
  }
  int wv = tid >> 6;
  if ((tid & 63) == 0) {
    #pragma unroll
    for (int t = 0; t < TT; ++t) { wr_s[wv][t] = bs[t]; wr_k[wv][t] = bk[t]; }
  }
  __syncthreads();
  if (tid < TT) {
    int t = tid;
    double s0 = wr_s[0][t]; int k0 = wr_k[0][t];
    #pragma unroll
    for (int w2 = 1; w2 < 4; ++w2) {
      double s1 = wr_s[w2][t]; int k1 = wr_k[w2][t];
      if (s1 > s0 || (s1 == s0 && k1 < k0)) { s0 = s1; k0 = k1; }
    }
    const float* crow = cb + (((g << 10) + k0) << 3);   // RAW codebook row
    double l = 0.0;
    #pragma unroll
    for (int e = 0; e < 8; ++e) {
      float qv = crow[e];
      zq_s[t * 8 + e] = qv;
      double dd = ze_d[t * 8 + e] - (double)qv;
      l = fma(dd, dd, l);
    }
    lossv[t] = (float)l;
  }
  __syncthreads();
  if (tid == 0) {
    float l = (lossv[0] + lossv[1] + lossv[2] + lossv[3]) * (1.0f / (T_ * D_ * G_));
    atomicAdd(loss_slots + b, l);        // commitment
    atomicAdd(loss_slots + 16 + b, l);   // codebook loss (numerically identical)
  }

  // ---------- phase 3: out = z_q @ proj_up, scatter-coalesced ----------
  float zqr[TT][8];
  #pragma unroll
  for (int t = 0; t < TT; ++t)
    #pragma unroll
    for (int e = 0; e < 8; ++e) zqr[t][e] = zq_s[t * 8 + e];

  #pragma unroll
  for (int j = 0; j < 8; ++j) {
    int dp = j * 256 + tid;
    int h = dp >> 7, ul = dp & 127;
    int u = (g << 7) + ul;
    int o = (u * 683) >> 17;
    int c = u - o * 192;
    float pv[8];
    #pragma unroll
    for (int e = 0; e < 8; ++e) pv[e] = pu_p[(g << 14) + (e << 11) + dp];
    size_t base = ((size_t)(b * SEQ_) + h * 512 + tc * (TT * OV_) + o) * 192 + c;
    #pragma unroll
    for (int t = 0; t < TT; ++t) {
      float v = 0.f;
      #pragma unroll
      for (int e = 0; e < 8; ++e) v = fmaf(zqr[t][e], pv[e], v);
      out[base + (size_t)(t * OV_ * 192)] = v;
    }
  }
}

extern "C" void kernel_launch(void* const* d_in, const int* in_sizes, int n_in,
                              void* d_out, int out_size, void* d_ws, size_t ws_size,
                              hipStream_t stream)
{
  const float* z  = (const float*)d_in[0];   // (B, SEQ, C)
  const float* pd = (const float*)d_in[1];   // (G, DG, D)
  const float* pu = (const float*)d_in[2];   // (G, D, DG)
  const float* cb = (const float*)d_in[3];   // (G, K, D)
  float* out = (float*)d_out;
  float* loss_slots = out + OUT_ELEMS;       // 16 commitment + 16 codebook

  float*  pd_p = (float*)d_ws;
  float*  pu_p = pd_p + 98304;
  double* cbn  = (double*)(pu_p + 98304);

  vq_prep<<<793, 256, 0, stream>>>(pd, pu, cb, pd_p, pu_p, cbn, loss_slots);
  dim3 grid(T_ / TT, G_, B_);
  vq_main<<<grid, 256, 0, stream>>>(z, cb, pd_p, pu_p, cbn, out, loss_slots);
}